// Round 2
// baseline (750.792 us; speedup 1.0000x reference)
//
#include <hip/hip_runtime.h>
#include <math.h>

// Problem constants (fixed by setup_inputs)
#define NTOK 16384
#define DDIM 4096
#define NEXP 64
#define KTOP 4
#define NGRP 8
#define LGRP 4

// GEMM config: lane = token, acc over all 64 experts, split-K
#define SPLITK 8
#define KPER (DDIM / SPLITK)    // 512 k per split
#define BKC 32                  // k per chunk
#define NCHUNK (KPER / BKC)     // 16

// ws layout (floats): partials [SPLITK][NEXP][NTOK]  (32 MB)

// ---------------- Kernel 0: zero counts ----------------
__global__ __launch_bounds__(64) void zero_counts_kernel(float* __restrict__ counts) {
    counts[threadIdx.x] = 0.0f;
}

// ---------------- Kernel 1: fp32 GEMM, no LDS ----------------
// grid = (NTOK/64) * SPLITK = 2048 blocks of 64 threads (1 wave).
// Wave: 64 tokens (lane=token) x 64 experts x KPER k.
// X: per-lane own-row loads (each float feeds 64 FMAs -> issue cost invisible).
// W: wave-uniform reads -> scalar loads; v_fmac v, s, v.
__global__ __launch_bounds__(64, 2) void gemm_kernel(
    const float* __restrict__ X, const float* __restrict__ W, float* __restrict__ part)
{
    const int lane = threadIdx.x;
    const int tb   = blockIdx.x >> 3;   // token block 0..255
    const int s    = blockIdx.x & 7;    // k-split    0..7
    const int tok  = tb * 64 + lane;
    const int kbase = s * KPER;

    const float* __restrict__ xrow = X + (size_t)tok * DDIM + kbase;

    float acc[NEXP];
    #pragma unroll
    for (int e = 0; e < NEXP; ++e) acc[e] = 0.0f;

    float4 xr[8], xn[8];
    #pragma unroll
    for (int q = 0; q < 8; ++q) xr[q] = *(const float4*)(xrow + q * 4);

    for (int c = 0; c < NCHUNK; ++c) {
        // prefetch next chunk's x (in flight across this chunk's 2048 FMAs)
        if (c < NCHUNK - 1) {
            #pragma unroll
            for (int q = 0; q < 8; ++q)
                xn[q] = *(const float4*)(xrow + (c + 1) * BKC + q * 4);
        }
        // W chunk base: uniform across lanes -> scalar loads
        const float* __restrict__ wp = W + kbase + c * BKC;
        #pragma unroll
        for (int q = 0; q < 8; ++q) {          // k-quad outer: 64 independent acc chains inside
            const float4 xq = xr[q];
            #pragma unroll
            for (int e = 0; e < NEXP; ++e) {
                const float4 w4 = *(const float4*)(wp + (size_t)e * DDIM + q * 4);
                acc[e] = fmaf(w4.x, xq.x, acc[e]);
                acc[e] = fmaf(w4.y, xq.y, acc[e]);
                acc[e] = fmaf(w4.z, xq.z, acc[e]);
                acc[e] = fmaf(w4.w, xq.w, acc[e]);
            }
        }
        #pragma unroll
        for (int q = 0; q < 8; ++q) xr[q] = xn[q];
    }

    // store partials [s][e][n]: lanes consecutive in n -> coalesced
    float* __restrict__ pp = part + (size_t)s * NEXP * NTOK + tok;
    #pragma unroll
    for (int e = 0; e < NEXP; ++e)
        pp[(size_t)e * NTOK] = acc[e];
}

// ---------------- Kernel 2: softmax + group-limited top-k routing ------------
__global__ __launch_bounds__(256) void route_kernel(
    const float* __restrict__ part, float* __restrict__ outW,
    float* __restrict__ outI, float* __restrict__ counts)
{
    __shared__ int hist[NEXP];
    const int tid = threadIdx.x;
    if (tid < NEXP) hist[tid] = 0;
    __syncthreads();

    const int lane = tid & 63;
    const int wv   = tid >> 6;   // wave 0..3
    const int tok_base = blockIdx.x * 32 + wv * 8;

    for (int t = 0; t < 8; ++t) {
        const int n = tok_base + t;
        // sum split-K partials: logit for expert `lane` (layout [s][e][n])
        float L = 0.0f;
        #pragma unroll
        for (int s = 0; s < SPLITK; ++s)
            L += part[((size_t)s * NEXP + lane) * NTOK + n];

        // softmax over 64 experts (wave = expert axis)
        float m = L;
        #pragma unroll
        for (int off = 32; off > 0; off >>= 1) m = fmaxf(m, __shfl_xor(m, off));
        float p = expf(L - m);
        float ssum = p;
        #pragma unroll
        for (int off = 32; off > 0; off >>= 1) ssum += __shfl_xor(ssum, off);
        float score = p / ssum;

        // group max within each 8-lane group
        float gm = score;
        gm = fmaxf(gm, __shfl_xor(gm, 1));
        gm = fmaxf(gm, __shfl_xor(gm, 2));
        gm = fmaxf(gm, __shfl_xor(gm, 4));

        // gather all 8 group maxima, serial top-4 groups (ties -> lower index)
        float ga[8];
        #pragma unroll
        for (int g = 0; g < 8; ++g) ga[g] = __shfl(gm, g * 8);
        unsigned selmask = 0u;
        #pragma unroll
        for (int r = 0; r < 4; ++r) {
            float best = -INFINITY; int bg = 0;
            #pragma unroll
            for (int g = 0; g < 8; ++g) {
                bool taken  = (selmask >> g) & 1u;
                bool better = (!taken) && (ga[g] > best);
                bg   = better ? g : bg;
                best = better ? ga[g] : best;
            }
            selmask |= (1u << bg);
        }

        // mask scores of non-selected groups, then wave-wide top-4 (ties -> lower idx)
        float ms = ((selmask >> (lane >> 3)) & 1u) ? score : -INFINITY;
        float wk[4]; int wi[4];
        #pragma unroll
        for (int r = 0; r < 4; ++r) {
            float v = ms; int ix = lane;
            #pragma unroll
            for (int off = 32; off > 0; off >>= 1) {
                float vo = __shfl_xor(v, off);
                int   io = __shfl_xor(ix, off);
                if (vo > v || (vo == v && io < ix)) { v = vo; ix = io; }
            }
            wk[r] = v; wi[r] = ix;
            if (lane == ix) ms = -INFINITY;
        }

        if (lane == 0) {
            *(float4*)&outW[(size_t)n * 4] = make_float4(wk[0], wk[1], wk[2], wk[3]);
            *(float4*)&outI[(size_t)n * 4] =
                make_float4((float)wi[0], (float)wi[1], (float)wi[2], (float)wi[3]);
            atomicAdd(&hist[wi[0]], 1);
            atomicAdd(&hist[wi[1]], 1);
            atomicAdd(&hist[wi[2]], 1);
            atomicAdd(&hist[wi[3]], 1);
        }
    }

    __syncthreads();
    if (tid < NEXP) atomicAdd(&counts[tid], (float)hist[tid]);
}

extern "C" void kernel_launch(void* const* d_in, const int* in_sizes, int n_in,
                              void* d_out, int out_size, void* d_ws, size_t ws_size,
                              hipStream_t stream) {
    const float* X = (const float*)d_in[0];
    const float* W = (const float*)d_in[1];

    float* outW   = (float*)d_out;                    // [N,4] weights
    float* outI   = outW + (size_t)NTOK * KTOP;       // [N,4] indices (as float)
    float* counts = outW + (size_t)2 * NTOK * KTOP;   // [64]  counts  (as float)

    float* part = (float*)d_ws;                       // [SPLITK][NEXP][NTOK] 32 MB

    zero_counts_kernel<<<1, 64, 0, stream>>>(counts);
    gemm_kernel<<<(NTOK / 64) * SPLITK, 64, 0, stream>>>(X, W, part);
    route_kernel<<<NTOK / 32, 256, 0, stream>>>(part, outW, outI, counts);
}

// Round 3
// 731.749 us; speedup vs baseline: 1.0260x; 1.0260x over previous
//
#include <hip/hip_runtime.h>
#include <math.h>

// Problem constants (fixed by setup_inputs)
#define NTOK 16384
#define DDIM 4096
#define NEXP 64
#define KTOP 4
#define NGRP 8
#define LGRP 4

// GEMM config
#define SPLITK 16
#define KPER (DDIM / SPLITK)   // 256 k per split
#define BK 32                  // k per W-stage chunk
#define NCH (KPER / BK)        // 8 chunks
#define ATOK 8                 // tokens per lane (acc rows)
#define BEXP 16                // experts per wave (acc cols)

// ws layout (floats): partials [SPLITK][NEXP][NTOK]  (64 MB)

// ---------------- Kernel 0: zero counts ----------------
__global__ __launch_bounds__(64) void zero_counts_kernel(float* __restrict__ counts) {
    counts[threadIdx.x] = 0.0f;
}

// ---------------- Kernel 1: fp32 GEMM ----------------
// 1 wave per block. Wave = 512 tokens (lane + 64j) x 16 experts x KPER k.
// X: global->register, per-lane rows, prefetched one k-quad ahead.
// W: global->LDS (reg-staged), consumed as wave-uniform broadcast ds_read_b128.
// No __syncthreads anywhere (single-wave block, wave-synchronous LDS).
__global__ __launch_bounds__(64, 2) void gemm_kernel(
    const float* __restrict__ X, const float* __restrict__ W, float* __restrict__ part)
{
    __shared__ float sW[2][BEXP][BK];   // 2 x 2 KB double buffer

    const int lane = threadIdx.x;
    const int bid  = blockIdx.x;
    const int s    = bid & (SPLITK - 1);        // k-split 0..15
    const int eq   = (bid >> 4) & 3;            // expert quarter 0..3
    const int tg   = bid >> 6;                  // token group 0..31
    const int tok0 = tg * 512;
    const int kbase = s * KPER;
    const int e0   = eq * BEXP;

    // X base for this lane's token 0; tokens are tok0 + lane + 64*j
    const float* __restrict__ xbase = X + (size_t)(tok0 + lane) * DDIM + kbase;
    // W staging source: lane covers expert e0+(lane>>2), k-bytes (lane&3)*8..+7
    const float* __restrict__ wsrc =
        W + (size_t)(e0 + (lane >> 2)) * DDIM + kbase + (lane & 3) * 8;
    const int wlr = lane >> 2;          // LDS row this lane writes
    const int wlc = (lane & 3) * 8;     // LDS col this lane writes

    float acc[ATOK][BEXP];
    #pragma unroll
    for (int j = 0; j < ATOK; ++j)
        #pragma unroll
        for (int e = 0; e < BEXP; ++e) acc[j][e] = 0.0f;

    // ---- stage chunk 0 into buf 0 ----
    float4 wra = *(const float4*)(wsrc);
    float4 wrb = *(const float4*)(wsrc + 4);
    *(float4*)&sW[0][wlr][wlc]     = wra;
    *(float4*)&sW[0][wlr][wlc + 4] = wrb;

    // ---- prefetch X quad 0 ----
    float4 xr[ATOK], xn[ATOK];
    #pragma unroll
    for (int j = 0; j < ATOK; ++j)
        xr[j] = *(const float4*)(xbase + (size_t)j * 64 * DDIM);

    for (int c = 0; c < NCH; ++c) {
        // issue next W chunk's global loads early (land during this chunk's FMAs)
        if (c + 1 < NCH) {
            wra = *(const float4*)(wsrc + (c + 1) * BK);
            wrb = *(const float4*)(wsrc + (c + 1) * BK + 4);
        }
        for (int kq = 0; kq < BK / 4; ++kq) {
            const int gkq = c * (BK / 4) + kq;
            // prefetch next X quad
            if (gkq + 1 < KPER / 4) {
                #pragma unroll
                for (int j = 0; j < ATOK; ++j)
                    xn[j] = *(const float4*)(xbase + (size_t)j * 64 * DDIM + (gkq + 1) * 4);
            }
            // 16 broadcast W reads, each feeding 32 FMAs
            #pragma unroll
            for (int e = 0; e < BEXP; ++e) {
                const float4 w4 = *(const float4*)&sW[c & 1][e][kq * 4];
                #pragma unroll
                for (int j = 0; j < ATOK; ++j) {
                    acc[j][e] = fmaf(xr[j].x, w4.x, acc[j][e]);
                    acc[j][e] = fmaf(xr[j].y, w4.y, acc[j][e]);
                    acc[j][e] = fmaf(xr[j].z, w4.z, acc[j][e]);
                    acc[j][e] = fmaf(xr[j].w, w4.w, acc[j][e]);
                }
            }
            #pragma unroll
            for (int j = 0; j < ATOK; ++j) xr[j] = xn[j];
        }
        // write next W chunk to the other LDS buffer (compiler inserts vmcnt wait)
        if (c + 1 < NCH) {
            *(float4*)&sW[(c + 1) & 1][wlr][wlc]     = wra;
            *(float4*)&sW[(c + 1) & 1][wlr][wlc + 4] = wrb;
        }
    }

    // ---- store partials [s][e][n]: lanes consecutive in n -> coalesced ----
    float* __restrict__ pp = part + ((size_t)s * NEXP + e0) * NTOK + tok0 + lane;
    #pragma unroll
    for (int e = 0; e < BEXP; ++e)
        #pragma unroll
        for (int j = 0; j < ATOK; ++j)
            pp[(size_t)e * NTOK + j * 64] = acc[j][e];
}

// ---------------- Kernel 2: softmax + group-limited top-k routing ------------
__global__ __launch_bounds__(256) void route_kernel(
    const float* __restrict__ part, float* __restrict__ outW,
    float* __restrict__ outI, float* __restrict__ counts)
{
    __shared__ int hist[NEXP];
    const int tid = threadIdx.x;
    if (tid < NEXP) hist[tid] = 0;
    __syncthreads();

    const int lane = tid & 63;
    const int wv   = tid >> 6;   // wave 0..3
    const int tok_base = blockIdx.x * 32 + wv * 8;

    for (int t = 0; t < 8; ++t) {
        const int n = tok_base + t;
        // sum split-K partials: logit for expert `lane` (layout [s][e][n])
        float L = 0.0f;
        #pragma unroll
        for (int s = 0; s < SPLITK; ++s)
            L += part[((size_t)s * NEXP + lane) * NTOK + n];

        // softmax over 64 experts (wave = expert axis)
        float m = L;
        #pragma unroll
        for (int off = 32; off > 0; off >>= 1) m = fmaxf(m, __shfl_xor(m, off));
        float p = expf(L - m);
        float ssum = p;
        #pragma unroll
        for (int off = 32; off > 0; off >>= 1) ssum += __shfl_xor(ssum, off);
        float score = p / ssum;

        // group max within each 8-lane group
        float gm = score;
        gm = fmaxf(gm, __shfl_xor(gm, 1));
        gm = fmaxf(gm, __shfl_xor(gm, 2));
        gm = fmaxf(gm, __shfl_xor(gm, 4));

        // gather all 8 group maxima, serial top-4 groups (ties -> lower index)
        float ga[8];
        #pragma unroll
        for (int g = 0; g < 8; ++g) ga[g] = __shfl(gm, g * 8);
        unsigned selmask = 0u;
        #pragma unroll
        for (int r = 0; r < 4; ++r) {
            float best = -INFINITY; int bg = 0;
            #pragma unroll
            for (int g = 0; g < 8; ++g) {
                bool taken  = (selmask >> g) & 1u;
                bool better = (!taken) && (ga[g] > best);
                bg   = better ? g : bg;
                best = better ? ga[g] : best;
            }
            selmask |= (1u << bg);
        }

        // mask scores of non-selected groups, then wave-wide top-4 (ties -> lower idx)
        float ms = ((selmask >> (lane >> 3)) & 1u) ? score : -INFINITY;
        float wk[4]; int wi[4];
        #pragma unroll
        for (int r = 0; r < 4; ++r) {
            float v = ms; int ix = lane;
            #pragma unroll
            for (int off = 32; off > 0; off >>= 1) {
                float vo = __shfl_xor(v, off);
                int   io = __shfl_xor(ix, off);
                if (vo > v || (vo == v && io < ix)) { v = vo; ix = io; }
            }
            wk[r] = v; wi[r] = ix;
            if (lane == ix) ms = -INFINITY;
        }

        if (lane == 0) {
            *(float4*)&outW[(size_t)n * 4] = make_float4(wk[0], wk[1], wk[2], wk[3]);
            *(float4*)&outI[(size_t)n * 4] =
                make_float4((float)wi[0], (float)wi[1], (float)wi[2], (float)wi[3]);
            atomicAdd(&hist[wi[0]], 1);
            atomicAdd(&hist[wi[1]], 1);
            atomicAdd(&hist[wi[2]], 1);
            atomicAdd(&hist[wi[3]], 1);
        }
    }

    __syncthreads();
    if (tid < NEXP) atomicAdd(&counts[tid], (float)hist[tid]);
}

extern "C" void kernel_launch(void* const* d_in, const int* in_sizes, int n_in,
                              void* d_out, int out_size, void* d_ws, size_t ws_size,
                              hipStream_t stream) {
    const float* X = (const float*)d_in[0];
    const float* W = (const float*)d_in[1];

    float* outW   = (float*)d_out;                    // [N,4] weights
    float* outI   = outW + (size_t)NTOK * KTOP;       // [N,4] indices (as float)
    float* counts = outW + (size_t)2 * NTOK * KTOP;   // [64]  counts  (as float)

    float* part = (float*)d_ws;                       // [SPLITK][NEXP][NTOK] 64 MB

    zero_counts_kernel<<<1, 64, 0, stream>>>(counts);
    gemm_kernel<<<32 * 4 * SPLITK, 64, 0, stream>>>(X, W, part);
    route_kernel<<<NTOK / 32, 256, 0, stream>>>(part, outW, outI, counts);
}

// Round 4
// 147.695 us; speedup vs baseline: 5.0834x; 4.9544x over previous
//
#include <hip/hip_runtime.h>
#include <math.h>

// Problem constants
#define NTOK 16384
#define DDIM 4096
#define NEXP 64
#define KTOP 4

// GEMM config
#define SPLITK 4
#define KPER (DDIM / SPLITK)   // 1024
#define BK 32                  // k per chunk (= one 16x16x32 MFMA k-step)
#define NCH (KPER / BK)        // 32 chunks
#define BM 128                 // tokens per block: 4 waves x 32 rows

typedef __attribute__((ext_vector_type(8))) short short8;
typedef __attribute__((ext_vector_type(4))) float f32x4;

// ws layout:
//   part [SPLITK][NTOK][NEXP] f32   = 16 MB
//   Whi  [NEXP][DDIM] ushort        = 512 KB
//   Wlo  [NEXP][DDIM] ushort        = 512 KB

__device__ __forceinline__ unsigned short f2bf_rtn(float x) {
    unsigned int b = __float_as_uint(x);
    return (unsigned short)((b + 0x7FFFu + ((b >> 16) & 1u)) >> 16);
}
__device__ __forceinline__ float bf2f(unsigned short h) {
    return __uint_as_float(((unsigned int)h) << 16);
}

// ---------------- Kernel 1: split W into bf16 hi/lo, zero counts -------------
__global__ __launch_bounds__(256) void prep_kernel(
    const float* __restrict__ W, unsigned short* __restrict__ Whi,
    unsigned short* __restrict__ Wlo, float* __restrict__ counts)
{
    int idx = blockIdx.x * 256 + threadIdx.x;   // 0 .. 64*4096
    float x = W[idx];
    unsigned short h = f2bf_rtn(x);
    float lo = x - bf2f(h);
    Whi[idx] = h;
    Wlo[idx] = f2bf_rtn(lo);
    if (blockIdx.x == 0 && threadIdx.x < NEXP) counts[threadIdx.x] = 0.0f;
}

// ---------------- Kernel 2: bf16x3-split MFMA GEMM, no LDS -------------------
// 512 blocks x 256 threads. Block = 128 tokens x 64 experts x KPER k.
// Wave w owns rows tok0 + w*32 .. +31 (2 m-groups of 16), all 64 experts.
// A: per-lane global->reg (wave reads 16 rows x 128 B full lines, read-once).
// B: Whi/Wlo global->reg, L2-resident (1 MB total).
__global__ __launch_bounds__(256, 2) void gemm_kernel(
    const float* __restrict__ X, const unsigned short* __restrict__ Whi,
    const unsigned short* __restrict__ Wlo, float* __restrict__ part)
{
    const int tid  = threadIdx.x;
    const int lane = tid & 63;
    const int w    = tid >> 6;
    const int tb   = blockIdx.x >> 2;          // token block 0..127
    const int s    = blockIdx.x & 3;           // k-split    0..3
    const int tok0 = tb * BM + w * 32;         // this wave's first row
    const int kbase = s * KPER;

    const int fr = lane & 15;                  // fragment row (m) / col (n)
    const int fg = lane >> 4;                  // k subgroup 0..3 (8 elems each)

    // A sources: row tok0 + mg*16 + fr, k = kbase + c*32 + fg*8  (8 fp32 = 32 B)
    const float* __restrict__ xa0 = X + (size_t)(tok0 + fr) * DDIM + kbase + fg * 8;
    const float* __restrict__ xa1 = xa0 + (size_t)16 * DDIM;
    // B source offset: expert ng*16 + fr, same k (8 bf16 = 16 B)
    const size_t woff = (size_t)fr * DDIM + kbase + fg * 8;

    f32x4 acc[2][4];
    #pragma unroll
    for (int mg = 0; mg < 2; ++mg)
        #pragma unroll
        for (int ng = 0; ng < 4; ++ng)
            acc[mg][ng] = (f32x4){0.f, 0.f, 0.f, 0.f};

    float4 xr[2][2], xn[2][2];
    short8 bh[4], bl[4], bhn[4], bln[4];

    // ---- load chunk 0 ----
    #pragma unroll
    for (int mg = 0; mg < 2; ++mg) {
        const float* xa = mg ? xa1 : xa0;
        xr[mg][0] = *(const float4*)(xa);
        xr[mg][1] = *(const float4*)(xa + 4);
    }
    #pragma unroll
    for (int ng = 0; ng < 4; ++ng) {
        bh[ng] = *(const short8*)(Whi + (size_t)ng * 16 * DDIM + woff);
        bl[ng] = *(const short8*)(Wlo + (size_t)ng * 16 * DDIM + woff);
    }

    for (int c = 0; c < NCH; ++c) {
        // ---- issue next chunk's loads (in flight across this chunk's MFMAs) ----
        if (c + 1 < NCH) {
            const int ko = (c + 1) * BK;
            #pragma unroll
            for (int mg = 0; mg < 2; ++mg) {
                const float* xa = (mg ? xa1 : xa0) + ko;
                xn[mg][0] = *(const float4*)(xa);
                xn[mg][1] = *(const float4*)(xa + 4);
            }
            #pragma unroll
            for (int ng = 0; ng < 4; ++ng) {
                bhn[ng] = *(const short8*)(Whi + (size_t)ng * 16 * DDIM + woff + ko);
                bln[ng] = *(const short8*)(Wlo + (size_t)ng * 16 * DDIM + woff + ko);
            }
        }

        // ---- split current A fp32 -> bf16 hi/lo fragments ----
        short8 ahi[2], alo[2];
        #pragma unroll
        for (int mg = 0; mg < 2; ++mg) {
            #pragma unroll
            for (int j = 0; j < 8; ++j) {
                float xv = (j < 4) ? ((j == 0) ? xr[mg][0].x : (j == 1) ? xr[mg][0].y
                                    : (j == 2) ? xr[mg][0].z : xr[mg][0].w)
                                   : ((j == 4) ? xr[mg][1].x : (j == 5) ? xr[mg][1].y
                                    : (j == 6) ? xr[mg][1].z : xr[mg][1].w);
                unsigned short h = f2bf_rtn(xv);
                float lo = xv - bf2f(h);
                ahi[mg][j] = (short)h;
                alo[mg][j] = (short)((__float_as_uint(lo) >> 16) & 0xFFFFu); // RTZ lo
            }
        }

        // ---- 24 MFMAs: hi*whi + hi*wlo + lo*whi ----
        #pragma unroll
        for (int mg = 0; mg < 2; ++mg) {
            #pragma unroll
            for (int ng = 0; ng < 4; ++ng) {
                acc[mg][ng] = __builtin_amdgcn_mfma_f32_16x16x32_bf16(
                    ahi[mg], bh[ng], acc[mg][ng], 0, 0, 0);
                acc[mg][ng] = __builtin_amdgcn_mfma_f32_16x16x32_bf16(
                    ahi[mg], bl[ng], acc[mg][ng], 0, 0, 0);
                acc[mg][ng] = __builtin_amdgcn_mfma_f32_16x16x32_bf16(
                    alo[mg], bh[ng], acc[mg][ng], 0, 0, 0);
            }
        }

        // ---- rotate ----
        #pragma unroll
        for (int mg = 0; mg < 2; ++mg) { xr[mg][0] = xn[mg][0]; xr[mg][1] = xn[mg][1]; }
        #pragma unroll
        for (int ng = 0; ng < 4; ++ng) { bh[ng] = bhn[ng]; bl[ng] = bln[ng]; }
    }

    // ---- store partials [s][tok][e]: 64-B segments per (fg,reg) -> coalesced ----
    // C/D layout: col = lane&15 (expert), row = fg*4 + reg (token)  [m89/m91]
    float* __restrict__ pp = part + ((size_t)s * NTOK + tok0) * NEXP;
    #pragma unroll
    for (int mg = 0; mg < 2; ++mg)
        #pragma unroll
        for (int ng = 0; ng < 4; ++ng)
            #pragma unroll
            for (int r = 0; r < 4; ++r)
                pp[(size_t)(mg * 16 + fg * 4 + r) * NEXP + ng * 16 + fr] = acc[mg][ng][r];
}

// ---------------- Kernel 3: softmax + group-limited top-k routing ------------
__global__ __launch_bounds__(256) void route_kernel(
    const float* __restrict__ part, float* __restrict__ outW,
    float* __restrict__ outI, float* __restrict__ counts)
{
    __shared__ int hist[NEXP];
    const int tid = threadIdx.x;
    if (tid < NEXP) hist[tid] = 0;
    __syncthreads();

    const int lane = tid & 63;
    const int wv   = tid >> 6;   // wave 0..3
    const int tok_base = blockIdx.x * 32 + wv * 8;

    for (int t = 0; t < 8; ++t) {
        const int n = tok_base + t;
        // sum split-K partials: logit for expert `lane` (layout [s][n][e])
        float L = 0.0f;
        #pragma unroll
        for (int s = 0; s < SPLITK; ++s)
            L += part[((size_t)s * NTOK + n) * NEXP + lane];

        // softmax over 64 experts (wave = expert axis)
        float m = L;
        #pragma unroll
        for (int off = 32; off > 0; off >>= 1) m = fmaxf(m, __shfl_xor(m, off));
        float p = expf(L - m);
        float ssum = p;
        #pragma unroll
        for (int off = 32; off > 0; off >>= 1) ssum += __shfl_xor(ssum, off);
        float score = p / ssum;

        // group max within each 8-lane group
        float gm = score;
        gm = fmaxf(gm, __shfl_xor(gm, 1));
        gm = fmaxf(gm, __shfl_xor(gm, 2));
        gm = fmaxf(gm, __shfl_xor(gm, 4));

        // gather all 8 group maxima, serial top-4 groups (ties -> lower index)
        float ga[8];
        #pragma unroll
        for (int g = 0; g < 8; ++g) ga[g] = __shfl(gm, g * 8);
        unsigned selmask = 0u;
        #pragma unroll
        for (int r = 0; r < 4; ++r) {
            float best = -INFINITY; int bg = 0;
            #pragma unroll
            for (int g = 0; g < 8; ++g) {
                bool taken  = (selmask >> g) & 1u;
                bool better = (!taken) && (ga[g] > best);
                bg   = better ? g : bg;
                best = better ? ga[g] : best;
            }
            selmask |= (1u << bg);
        }

        // mask non-selected groups, wave-wide top-4 (ties -> lower idx)
        float ms = ((selmask >> (lane >> 3)) & 1u) ? score : -INFINITY;
        float wk[4]; int wi[4];
        #pragma unroll
        for (int r = 0; r < 4; ++r) {
            float v = ms; int ix = lane;
            #pragma unroll
            for (int off = 32; off > 0; off >>= 1) {
                float vo = __shfl_xor(v, off);
                int   io = __shfl_xor(ix, off);
                if (vo > v || (vo == v && io < ix)) { v = vo; ix = io; }
            }
            wk[r] = v; wi[r] = ix;
            if (lane == ix) ms = -INFINITY;
        }

        if (lane == 0) {
            *(float4*)&outW[(size_t)n * 4] = make_float4(wk[0], wk[1], wk[2], wk[3]);
            *(float4*)&outI[(size_t)n * 4] =
                make_float4((float)wi[0], (float)wi[1], (float)wi[2], (float)wi[3]);
            atomicAdd(&hist[wi[0]], 1);
            atomicAdd(&hist[wi[1]], 1);
            atomicAdd(&hist[wi[2]], 1);
            atomicAdd(&hist[wi[3]], 1);
        }
    }

    __syncthreads();
    if (tid < NEXP) atomicAdd(&counts[tid], (float)hist[tid]);
}

extern "C" void kernel_launch(void* const* d_in, const int* in_sizes, int n_in,
                              void* d_out, int out_size, void* d_ws, size_t ws_size,
                              hipStream_t stream) {
    const float* X = (const float*)d_in[0];
    const float* W = (const float*)d_in[1];

    float* outW   = (float*)d_out;                    // [N,4] weights
    float* outI   = outW + (size_t)NTOK * KTOP;       // [N,4] indices (as float)
    float* counts = outW + (size_t)2 * NTOK * KTOP;   // [64]  counts  (as float)

    float*          part = (float*)d_ws;                              // 16 MB
    unsigned short* Whi  = (unsigned short*)(part + (size_t)SPLITK * NTOK * NEXP);
    unsigned short* Wlo  = Whi + (size_t)NEXP * DDIM;

    prep_kernel<<<(NEXP * DDIM) / 256, 256, 0, stream>>>(W, Whi, Wlo, counts);
    gemm_kernel<<<(NTOK / BM) * SPLITK, 256, 0, stream>>>(X, Whi, Wlo, part);
    route_kernel<<<NTOK / 32, 256, 0, stream>>>(part, outW, outI, counts);
}

// Round 5
// 105.381 us; speedup vs baseline: 7.1246x; 1.4015x over previous
//
#include <hip/hip_runtime.h>
#include <math.h>

// Problem constants
#define NTOK 16384
#define DDIM 4096
#define NEXP 64
#define KTOP 4

// GEMM config
#define SPLITK 8
#define KPER (DDIM / SPLITK)   // 512 k per split
#define BK 32                  // k per chunk (one 16x16x32 MFMA k-step)
#define NCH (KPER / BK)        // 16 chunks
#define BMB 256                // tokens per block = 8 waves x 32 rows

typedef __attribute__((ext_vector_type(8))) short short8;
typedef __attribute__((ext_vector_type(4))) float f32x4;

// ws layout:
//   part [NTOK][SPLITK][NEXP] f32 = 32 MB
//   Whi  [NEXP][DDIM] ushort      = 512 KB
//   Wlo  [NEXP][DDIM] ushort      = 512 KB

__device__ __forceinline__ unsigned short f2bf_rtn(float x) {
    unsigned int b = __float_as_uint(x);
    return (unsigned short)((b + 0x7FFFu + ((b >> 16) & 1u)) >> 16);
}
__device__ __forceinline__ float bf2f(unsigned short h) {
    return __uint_as_float(((unsigned int)h) << 16);
}

// ---------------- Kernel 1: split W into bf16 hi/lo, zero counts -------------
__global__ __launch_bounds__(256) void prep_kernel(
    const float* __restrict__ W, unsigned short* __restrict__ Whi,
    unsigned short* __restrict__ Wlo, float* __restrict__ counts)
{
    int idx = blockIdx.x * 256 + threadIdx.x;   // 0 .. 64*4096
    float x = W[idx];
    unsigned short h = f2bf_rtn(x);
    float lo = x - bf2f(h);
    Whi[idx] = h;
    Wlo[idx] = f2bf_rtn(lo);
    if (blockIdx.x == 0 && threadIdx.x < NEXP) counts[threadIdx.x] = 0.0f;
}

// ---------------- Kernel 2: bf16x3-split MFMA GEMM, W-slice in LDS -----------
// 512 blocks x 512 threads (8 waves), 1 block/CU (128 KB LDS), 2 rounds.
// Block = 256 tokens x 64 experts x KPER k.  X read exactly once device-wide.
// W slice (hi+lo) staged to LDS once (XOR-swizzled), then barrier-free loop:
// per chunk/wave: 4 A-loads (depth-2 prefetch) + 8 ds_read_b128 + 24 MFMA.
__global__ __launch_bounds__(512, 2) void gemm_kernel(
    const float* __restrict__ X, const unsigned short* __restrict__ Whi,
    const unsigned short* __restrict__ Wlo, float* __restrict__ part)
{
    __shared__ unsigned short sHi[NEXP * KPER];   // 64 KB
    __shared__ unsigned short sLo[NEXP * KPER];   // 64 KB

    const int tid  = threadIdx.x;
    const int lane = tid & 63;
    const int w    = tid >> 6;                 // wave 0..7
    const int tb   = blockIdx.x >> 3;          // token block 0..63
    const int s    = blockIdx.x & 7;           // k-split    0..7
    const int kbase = s * KPER;
    const int tok0 = tb * BMB + w * 32;        // this wave's first row

    // ---- stage W slice: thread t covers expert e=t>>3, pieces j=t&7 (+64i) --
    {
        const int e = tid >> 3;
        const int j = tid & 7;
        const unsigned short* gh = Whi + (size_t)e * DDIM + kbase + j * 8;
        const unsigned short* gl = Wlo + (size_t)e * DDIM + kbase + j * 8;
        const int m = (e & 7) * 8;             // XOR swizzle (ushort units)
        #pragma unroll
        for (int i = 0; i < 8; ++i) {
            const int kk = j * 8 + i * 64;
            short8 vh = *(const short8*)(gh + i * 64);
            short8 vl = *(const short8*)(gl + i * 64);
            *(short8*)&sHi[e * KPER + (kk ^ m)] = vh;
            *(short8*)&sLo[e * KPER + (kk ^ m)] = vl;
        }
    }
    __syncthreads();

    const int fr = lane & 15;                  // fragment row (token) / col (expert)
    const int fg = lane >> 4;                  // k subgroup 0..3
    // swizzled k-offset component (c*32 is XORed per chunk at compile time)
    const int kx = (fg * 8) ^ ((fr & 7) * 8);

    // A sources: row tok0 + mg*16 + fr, k = kbase + c*32 + fg*8
    const float* __restrict__ xa0 = X + (size_t)(tok0 + fr) * DDIM + kbase + fg * 8;
    const float* __restrict__ xa1 = xa0 + (size_t)16 * DDIM;

    f32x4 acc[2][4];
    #pragma unroll
    for (int mg = 0; mg < 2; ++mg)
        #pragma unroll
        for (int ng = 0; ng < 4; ++ng)
            acc[mg][ng] = (f32x4){0.f, 0.f, 0.f, 0.f};

    // A pipeline buffers, fully unrolled (all indices compile-time -> SSA regs)
    float4 xq[NCH][2][2];

#define LOADA(c)                                                            \
    {                                                                       \
        xq[c][0][0] = *(const float4*)(xa0 + (c) * BK);                     \
        xq[c][0][1] = *(const float4*)(xa0 + (c) * BK + 4);                 \
        xq[c][1][0] = *(const float4*)(xa1 + (c) * BK);                     \
        xq[c][1][1] = *(const float4*)(xa1 + (c) * BK + 4);                 \
    }

    LOADA(0)
    LOADA(1)

    #pragma unroll
    for (int c = 0; c < NCH; ++c) {
        if (c + 2 < NCH) LOADA(c + 2)          // depth-2 prefetch

        // ---- split A fp32 -> bf16 hi/lo fragments ----
        short8 ahi[2], alo[2];
        #pragma unroll
        for (int mg = 0; mg < 2; ++mg) {
            #pragma unroll
            for (int j = 0; j < 8; ++j) {
                const float4 q = xq[c][mg][j >> 2];
                float xv = ((j & 3) == 0) ? q.x : ((j & 3) == 1) ? q.y
                         : ((j & 3) == 2) ? q.z : q.w;
                unsigned short h = f2bf_rtn(xv);
                float lo = xv - bf2f(h);
                ahi[mg][j] = (short)h;
                alo[mg][j] = (short)(__float_as_uint(lo) >> 16);   // RTZ lo
            }
        }

        // ---- B from LDS (swizzled) + 24 MFMAs ----
        #pragma unroll
        for (int ng = 0; ng < 4; ++ng) {
            const int bE = (ng * 16 + fr) * KPER;
            const int t  = (c * BK) ^ kx;      // c*BK compile-time under unroll
            const short8 bh = *(const short8*)(sHi + bE + t);
            const short8 bl = *(const short8*)(sLo + bE + t);
            #pragma unroll
            for (int mg = 0; mg < 2; ++mg) {
                acc[mg][ng] = __builtin_amdgcn_mfma_f32_16x16x32_bf16(
                    ahi[mg], bh, acc[mg][ng], 0, 0, 0);
                acc[mg][ng] = __builtin_amdgcn_mfma_f32_16x16x32_bf16(
                    ahi[mg], bl, acc[mg][ng], 0, 0, 0);
                acc[mg][ng] = __builtin_amdgcn_mfma_f32_16x16x32_bf16(
                    alo[mg], bh, acc[mg][ng], 0, 0, 0);
            }
        }
    }
#undef LOADA

    // ---- store partials [n][s][e] (route reads 2 KB contiguous per token) ---
    // C/D layout: col = lane&15 (expert), row = fg*4 + reg (token)
    #pragma unroll
    for (int mg = 0; mg < 2; ++mg)
        #pragma unroll
        for (int r = 0; r < 4; ++r) {
            const int row = tok0 + mg * 16 + fg * 4 + r;
            float* __restrict__ pp = part + ((size_t)row * SPLITK + s) * NEXP;
            #pragma unroll
            for (int ng = 0; ng < 4; ++ng)
                pp[ng * 16 + fr] = acc[mg][ng][r];
        }
}

// ---------------- Kernel 3: softmax + group-limited top-k routing ------------
__global__ __launch_bounds__(256) void route_kernel(
    const float* __restrict__ part, float* __restrict__ outW,
    float* __restrict__ outI, float* __restrict__ counts)
{
    __shared__ int hist[NEXP];
    const int tid = threadIdx.x;
    if (tid < NEXP) hist[tid] = 0;
    __syncthreads();

    const int lane = tid & 63;
    const int wv   = tid >> 6;   // wave 0..3
    const int tok_base = blockIdx.x * 32 + wv * 8;

    for (int t = 0; t < 8; ++t) {
        const int n = tok_base + t;
        // sum split-K partials (layout [n][s][e]): 2 KB contiguous per token
        float L = 0.0f;
        #pragma unroll
        for (int s = 0; s < SPLITK; ++s)
            L += part[((size_t)n * SPLITK + s) * NEXP + lane];

        // softmax over 64 experts (wave = expert axis)
        float m = L;
        #pragma unroll
        for (int off = 32; off > 0; off >>= 1) m = fmaxf(m, __shfl_xor(m, off));
        float p = expf(L - m);
        float ssum = p;
        #pragma unroll
        for (int off = 32; off > 0; off >>= 1) ssum += __shfl_xor(ssum, off);
        float score = p / ssum;

        // group max within each 8-lane group
        float gm = score;
        gm = fmaxf(gm, __shfl_xor(gm, 1));
        gm = fmaxf(gm, __shfl_xor(gm, 2));
        gm = fmaxf(gm, __shfl_xor(gm, 4));

        // gather all 8 group maxima, serial top-4 groups (ties -> lower index)
        float ga[8];
        #pragma unroll
        for (int g = 0; g < 8; ++g) ga[g] = __shfl(gm, g * 8);
        unsigned selmask = 0u;
        #pragma unroll
        for (int r = 0; r < 4; ++r) {
            float best = -INFINITY; int bg = 0;
            #pragma unroll
            for (int g = 0; g < 8; ++g) {
                bool taken  = (selmask >> g) & 1u;
                bool better = (!taken) && (ga[g] > best);
                bg   = better ? g : bg;
                best = better ? ga[g] : best;
            }
            selmask |= (1u << bg);
        }

        // mask non-selected groups, wave-wide top-4 (ties -> lower idx)
        float ms = ((selmask >> (lane >> 3)) & 1u) ? score : -INFINITY;
        float wk[4]; int wi[4];
        #pragma unroll
        for (int r = 0; r < 4; ++r) {
            float v = ms; int ix = lane;
            #pragma unroll
            for (int off = 32; off > 0; off >>= 1) {
                float vo = __shfl_xor(v, off);
                int   io = __shfl_xor(ix, off);
                if (vo > v || (vo == v && io < ix)) { v = vo; ix = io; }
            }
            wk[r] = v; wi[r] = ix;
            if (lane == ix) ms = -INFINITY;
        }

        if (lane == 0) {
            *(float4*)&outW[(size_t)n * 4] = make_float4(wk[0], wk[1], wk[2], wk[3]);
            *(float4*)&outI[(size_t)n * 4] =
                make_float4((float)wi[0], (float)wi[1], (float)wi[2], (float)wi[3]);
            atomicAdd(&hist[wi[0]], 1);
            atomicAdd(&hist[wi[1]], 1);
            atomicAdd(&hist[wi[2]], 1);
            atomicAdd(&hist[wi[3]], 1);
        }
    }

    __syncthreads();
    if (tid < NEXP) atomicAdd(&counts[tid], (float)hist[tid]);
}

extern "C" void kernel_launch(void* const* d_in, const int* in_sizes, int n_in,
                              void* d_out, int out_size, void* d_ws, size_t ws_size,
                              hipStream_t stream) {
    const float* X = (const float*)d_in[0];
    const float* W = (const float*)d_in[1];

    float* outW   = (float*)d_out;                    // [N,4] weights
    float* outI   = outW + (size_t)NTOK * KTOP;       // [N,4] indices (as float)
    float* counts = outW + (size_t)2 * NTOK * KTOP;   // [64]  counts  (as float)

    float*          part = (float*)d_ws;                              // 32 MB
    unsigned short* Whi  = (unsigned short*)(part + (size_t)NTOK * SPLITK * NEXP);
    unsigned short* Wlo  = Whi + (size_t)NEXP * DDIM;

    prep_kernel<<<(NEXP * DDIM) / 256, 256, 0, stream>>>(W, Whi, Wlo, counts);
    gemm_kernel<<<(NTOK / BMB) * SPLITK, 512, 0, stream>>>(X, Whi, Wlo, part);
    route_kernel<<<NTOK / 32, 256, 0, stream>>>(part, outW, outI, counts);
}